// Round 4
// baseline (65.393 us; speedup 1.0000x reference)
//
#include <hip/hip_runtime.h>
#include <math.h>

// Sampler: iterative Gumbel-softmax relaxed top-k.
// att: [B=256, N=1024, M=4] f32; k=128; out: khot [B,N,M] f32.
// Per (b,m) column over N: ag0 = att + gumbel(key 42, threefry2x32);
//   repeat k: ag += log(max(1-oh,EPS)); oh = softmax(2*ag); khot += oh.
// We carry w = exp(2*ag - M0) and update w *= mask^2 (exactly equivalent),
// so the k-loop has NO transcendentals.
//
// PRNG: JAX threefry2x32, key (0,42), partitionable path:
// counter = iota_2x32_shape -> (hi=0, lo=i); 32-bit draw = bits1 ^ bits2
// (XOR of BOTH cipher output words — _threefry_random_bits_partitionable).

#define N_NODES 1024

__device__ __forceinline__ unsigned rotl32(unsigned x, int r) {
  return (x << r) | (x >> (32 - r));
}

// JAX/Random123 Threefry-2x32, 20 rounds.
__device__ __forceinline__ void threefry2x32(unsigned k0, unsigned k1,
                                             unsigned& x0, unsigned& x1) {
  const unsigned ks0 = k0, ks1 = k1, ks2 = k0 ^ k1 ^ 0x1BD11BDAu;
  x0 += ks0; x1 += ks1;
  // group 1: rotations 13,15,26,6
  x0 += x1; x1 = rotl32(x1, 13); x1 ^= x0;
  x0 += x1; x1 = rotl32(x1, 15); x1 ^= x0;
  x0 += x1; x1 = rotl32(x1, 26); x1 ^= x0;
  x0 += x1; x1 = rotl32(x1, 6);  x1 ^= x0;
  x0 += ks1; x1 += ks2 + 1u;
  // group 2: 17,29,16,24
  x0 += x1; x1 = rotl32(x1, 17); x1 ^= x0;
  x0 += x1; x1 = rotl32(x1, 29); x1 ^= x0;
  x0 += x1; x1 = rotl32(x1, 16); x1 ^= x0;
  x0 += x1; x1 = rotl32(x1, 24); x1 ^= x0;
  x0 += ks2; x1 += ks0 + 2u;
  // group 3: 13,15,26,6
  x0 += x1; x1 = rotl32(x1, 13); x1 ^= x0;
  x0 += x1; x1 = rotl32(x1, 15); x1 ^= x0;
  x0 += x1; x1 = rotl32(x1, 26); x1 ^= x0;
  x0 += x1; x1 = rotl32(x1, 6);  x1 ^= x0;
  x0 += ks0; x1 += ks1 + 3u;
  // group 4: 17,29,16,24
  x0 += x1; x1 = rotl32(x1, 17); x1 ^= x0;
  x0 += x1; x1 = rotl32(x1, 29); x1 ^= x0;
  x0 += x1; x1 = rotl32(x1, 16); x1 ^= x0;
  x0 += x1; x1 = rotl32(x1, 24); x1 ^= x0;
  x0 += ks1; x1 += ks2 + 4u;
  // group 5: 13,15,26,6
  x0 += x1; x1 = rotl32(x1, 13); x1 ^= x0;
  x0 += x1; x1 = rotl32(x1, 15); x1 ^= x0;
  x0 += x1; x1 = rotl32(x1, 26); x1 ^= x0;
  x0 += x1; x1 = rotl32(x1, 6);  x1 ^= x0;
  x0 += ks2; x1 += ks0 + 5u;
}

__global__ __launch_bounds__(256)
void Sampler_72619307040792_kernel(const float* __restrict__ att,
                                   const int* __restrict__ kp,
                                   float* __restrict__ out) {
  const int col = blockIdx.x;        // 0..1023 = b*4 + m
  const int b = col >> 2;
  const int m = col & 3;
  const int tid = threadIdx.x;       // 256 threads, 4 nodes each
  const int lane = tid & 63;
  const int wid = tid >> 6;
  const int k = *kp;

  const float EPS = __uint_as_float(0x00800000u);  // f32 tiny (normal min)

  __shared__ float red[8];           // 2 parity slots x 4 waves

  float g[4], w[4], kh[4], oh[4];

  // --- init: load att, Gumbel noise via JAX threefry (partitionable path,
  //     counter (0, i), bits = out0 ^ out1), fold temperature (x2)
#pragma unroll
  for (int j = 0; j < 4; ++j) {
    const int n = tid * 4 + j;
    const unsigned idx = (unsigned)(b * 4096 + n * 4 + m);
    unsigned c0 = 0u, c1 = idx;      // counter = (hi=0, lo=i)
    threefry2x32(0u, 42u, c0, c1);
    const unsigned bits = c0 ^ c1;   // XOR of both cipher output words
    const float u = __uint_as_float((bits >> 9) | 0x3F800000u) - 1.0f;
    const float gum = -logf(-logf(u + EPS));
    g[j] = 2.0f * (att[idx] + gum);  // = (att_gumbel)/TEMPERATURE
    kh[j] = 0.0f;
    oh[j] = 0.0f;
  }

  // --- column max (once): M0 = max over 1024 nodes of g
  float v = fmaxf(fmaxf(g[0], g[1]), fmaxf(g[2], g[3]));
#pragma unroll
  for (int s = 1; s < 64; s <<= 1) v = fmaxf(v, __shfl_xor(v, s, 64));
  if (lane == 0) red[wid] = v;
  __syncthreads();
  const float M0 = fmaxf(fmaxf(red[0], red[1]), fmaxf(red[2], red[3]));
  __syncthreads();

#pragma unroll
  for (int j = 0; j < 4; ++j) w[j] = expf(g[j] - M0);

  // --- k iterations; w carries exp(2*ag - M0) exactly (w *= mask^2)
  for (int it = 0; it < k; ++it) {
#pragma unroll
    for (int j = 0; j < 4; ++j) {
      const float mask = fmaxf(1.0f - oh[j], EPS);
      w[j] *= mask * mask;
    }
    float s = (w[0] + w[1]) + (w[2] + w[3]);
#pragma unroll
    for (int sh = 1; sh < 64; sh <<= 1) s += __shfl_xor(s, sh, 64);
    const int p = (it & 1) << 2;
    if (lane == 0) red[p + wid] = s;
    __syncthreads();
    const float S = (red[p + 0] + red[p + 1]) + (red[p + 2] + red[p + 3]);
    const float rinv = 1.0f / S;
#pragma unroll
    for (int j = 0; j < 4; ++j) {
      oh[j] = w[j] * rinv;
      kh[j] += oh[j];
    }
  }

  // --- store khot
#pragma unroll
  for (int j = 0; j < 4; ++j) {
    const int n = tid * 4 + j;
    out[b * 4096 + n * 4 + m] = kh[j];
  }
}

extern "C" void kernel_launch(void* const* d_in, const int* in_sizes, int n_in,
                              void* d_out, int out_size, void* d_ws, size_t ws_size,
                              hipStream_t stream) {
  const float* att = (const float*)d_in[0];
  const int* kp = (const int*)d_in[1];
  float* out = (float*)d_out;
  const int cols = out_size / N_NODES;  // 256*4 = 1024 independent columns
  Sampler_72619307040792_kernel<<<cols, 256, 0, stream>>>(att, kp, out);
}

// Round 5
// 36.609 us; speedup vs baseline: 1.7863x; 1.7863x over previous
//
#include <hip/hip_runtime.h>
#include <math.h>

// Sampler: iterative Gumbel-softmax relaxed top-k.
// att: [B=256, N=1024, M=4] f32; k=128; out: khot [B,N,M] f32.
// Column (b,m) over N=1024 nodes. w carries exp(2*ag - M0); per iteration:
//   kh += w*rinv_prev; mask = max(1 - w*rinv_prev, EPS); w *= mask^2; S = sum w.
// (identical math to the verified R4 kernel, accumulation deferred one iter)
//
// Layout: one WAVE per column (64 lanes x 16 elems) -> no __syncthreads, no LDS.
// Reduction: DPP row_shr 1/2/4/8 + row_bcast 15/31 + readlane(63).
// PRNG: JAX threefry2x32 key (0,42), partitionable path: counter (0,i),
// bits = out0 ^ out1  (verified passing in R4).

#define N_NODES 1024

__device__ __forceinline__ unsigned rotl32(unsigned x, int r) {
  return (x << r) | (x >> (32 - r));
}

// JAX/Random123 Threefry-2x32, 20 rounds.
__device__ __forceinline__ void threefry2x32(unsigned k0, unsigned k1,
                                             unsigned& x0, unsigned& x1) {
  const unsigned ks0 = k0, ks1 = k1, ks2 = k0 ^ k1 ^ 0x1BD11BDAu;
  x0 += ks0; x1 += ks1;
  x0 += x1; x1 = rotl32(x1, 13); x1 ^= x0;
  x0 += x1; x1 = rotl32(x1, 15); x1 ^= x0;
  x0 += x1; x1 = rotl32(x1, 26); x1 ^= x0;
  x0 += x1; x1 = rotl32(x1, 6);  x1 ^= x0;
  x0 += ks1; x1 += ks2 + 1u;
  x0 += x1; x1 = rotl32(x1, 17); x1 ^= x0;
  x0 += x1; x1 = rotl32(x1, 29); x1 ^= x0;
  x0 += x1; x1 = rotl32(x1, 16); x1 ^= x0;
  x0 += x1; x1 = rotl32(x1, 24); x1 ^= x0;
  x0 += ks2; x1 += ks0 + 2u;
  x0 += x1; x1 = rotl32(x1, 13); x1 ^= x0;
  x0 += x1; x1 = rotl32(x1, 15); x1 ^= x0;
  x0 += x1; x1 = rotl32(x1, 26); x1 ^= x0;
  x0 += x1; x1 = rotl32(x1, 6);  x1 ^= x0;
  x0 += ks0; x1 += ks1 + 3u;
  x0 += x1; x1 = rotl32(x1, 17); x1 ^= x0;
  x0 += x1; x1 = rotl32(x1, 29); x1 ^= x0;
  x0 += x1; x1 = rotl32(x1, 16); x1 ^= x0;
  x0 += x1; x1 = rotl32(x1, 24); x1 ^= x0;
  x0 += ks1; x1 += ks2 + 4u;
  x0 += x1; x1 = rotl32(x1, 13); x1 ^= x0;
  x0 += x1; x1 = rotl32(x1, 15); x1 ^= x0;
  x0 += x1; x1 = rotl32(x1, 26); x1 ^= x0;
  x0 += x1; x1 = rotl32(x1, 6);  x1 ^= x0;
  x0 += ks2; x1 += ks0 + 5u;
}

// --- DPP wave-64 reductions (VALU-rate; no LDS) ------------------------------
template <int CTRL>
__device__ __forceinline__ float dpp_sum_step(float v) {
  int t = __builtin_amdgcn_update_dpp(0, __float_as_int(v), CTRL, 0xf, 0xf, true);
  return v + __int_as_float(t);
}
template <int CTRL>
__device__ __forceinline__ float dpp_max_step(float v) {
  int iv = __float_as_int(v);
  int t = __builtin_amdgcn_update_dpp(iv, iv, CTRL, 0xf, 0xf, false);
  return fmaxf(v, __int_as_float(t));
}

__device__ __forceinline__ float wave_sum64(float v) {
  v = dpp_sum_step<0x111>(v);  // row_shr:1
  v = dpp_sum_step<0x112>(v);  // row_shr:2
  v = dpp_sum_step<0x114>(v);  // row_shr:4
  v = dpp_sum_step<0x118>(v);  // row_shr:8  -> lane 15 of each row has row sum
  v = dpp_sum_step<0x142>(v);  // row_bcast:15
  v = dpp_sum_step<0x143>(v);  // row_bcast:31 -> lane 63 has full sum
  return __int_as_float(__builtin_amdgcn_readlane(__float_as_int(v), 63));
}
__device__ __forceinline__ float wave_max64(float v) {
  v = dpp_max_step<0x111>(v);
  v = dpp_max_step<0x112>(v);
  v = dpp_max_step<0x114>(v);
  v = dpp_max_step<0x118>(v);
  v = dpp_max_step<0x142>(v);
  v = dpp_max_step<0x143>(v);
  return __int_as_float(__builtin_amdgcn_readlane(__float_as_int(v), 63));
}

__global__ __launch_bounds__(256)
void Sampler_72619307040792_kernel(const float* __restrict__ att,
                                   const int* __restrict__ kp,
                                   float* __restrict__ out) {
  const int b = blockIdx.x;          // one graph per block
  const int tid = threadIdx.x;
  const int lane = tid & 63;
  const int m = tid >> 6;            // one column (b,m) per WAVE
  const int k = *kp;

  const float EPS = __uint_as_float(0x00800000u);  // f32 tiny (normal min)
  const int base = b * 4096 + m;     // + n*4 indexes element n of this column

  float w[16], kh[16], g[16];

  // --- init: att + Gumbel noise (threefry partitionable, bits = x0^x1), x2
#pragma unroll
  for (int j = 0; j < 16; ++j) {
    const int n = j * 64 + lane;
    const unsigned idx = (unsigned)(base + n * 4);
    unsigned c0 = 0u, c1 = idx;
    threefry2x32(0u, 42u, c0, c1);
    const unsigned bits = c0 ^ c1;
    const float u = __uint_as_float((bits >> 9) | 0x3F800000u) - 1.0f;
    const float gum = -logf(-logf(u + EPS));
    g[j] = 2.0f * (att[idx] + gum);
    kh[j] = 0.0f;
  }

  if (k <= 0) {
#pragma unroll
    for (int j = 0; j < 16; ++j) out[base + (j * 64 + lane) * 4] = 0.0f;
    return;
  }

  // --- column max M0 (exact; uniform shift)
  float mx = g[0];
#pragma unroll
  for (int j = 1; j < 16; ++j) mx = fmaxf(mx, g[j]);
  mx = wave_max64(mx);

  // --- w = exp(g - M0); first reduce (iteration 1: mask is identity)
  float sa[4] = {0.f, 0.f, 0.f, 0.f};
#pragma unroll
  for (int j = 0; j < 16; ++j) {
    w[j] = expf(g[j] - mx);
    sa[j & 3] += w[j];
  }
  float S = wave_sum64((sa[0] + sa[1]) + (sa[2] + sa[3]));
  float rinv = __builtin_amdgcn_rcpf(S);

  // --- iterations 2..k: kh += oh_prev; mask; w *= mask^2; reduce
  for (int it = 1; it < k; ++it) {
    float ta[4] = {0.f, 0.f, 0.f, 0.f};
#pragma unroll
    for (int j = 0; j < 16; ++j) {
      kh[j] = fmaf(w[j], rinv, kh[j]);           // khot += oh
      float mk = fmaf(-w[j], rinv, 1.0f);        // 1 - oh
      mk = fmaxf(mk, EPS);
      const float wm = w[j] * mk;
      w[j] = wm * mk;                            // w *= mask^2
      ta[j & 3] += w[j];
    }
    S = wave_sum64((ta[0] + ta[1]) + (ta[2] + ta[3]));
    rinv = __builtin_amdgcn_rcpf(S);
  }

  // --- final accumulation (oh_k) + store
#pragma unroll
  for (int j = 0; j < 16; ++j) {
    kh[j] = fmaf(w[j], rinv, kh[j]);
    out[base + (j * 64 + lane) * 4] = kh[j];
  }
}

extern "C" void kernel_launch(void* const* d_in, const int* in_sizes, int n_in,
                              void* d_out, int out_size, void* d_ws, size_t ws_size,
                              hipStream_t stream) {
  const float* att = (const float*)d_in[0];
  const int* kp = (const int*)d_in[1];
  float* out = (float*)d_out;
  const int blocks = out_size / (N_NODES * 4);  // 256 graphs; 4 columns/block
  Sampler_72619307040792_kernel<<<blocks, 256, 0, stream>>>(att, kp, out);
}

// Round 6
// 31.780 us; speedup vs baseline: 2.0577x; 1.1519x over previous
//
#include <hip/hip_runtime.h>
#include <math.h>

// Sampler: iterative Gumbel-softmax relaxed top-k.
// att: [B=256, N=1024, M=4] f32; k=128; out: khot [B,N,M] f32.
// One WAVE per (b,m) column (64 lanes x 16 elems), 64-thread blocks,
// __launch_bounds__(64,1) -> full VGPR budget so the 16-element phases
// interleave (R5 was serialized at VGPR=36, latency-bound).
// w carries exp(2*ag - M0); per iteration (exact algebra of the reference):
//   o = w*rinv; kh += o; w *= (1-o)^2; S = sum w; rinv = rcp(S).
// Mask clamp dropped: (1-o)^2 >= 0 and w underflow->0 matches reference.
// PRNG: JAX threefry2x32 key (0,42), partitionable: counter (0,i),
// bits = out0 ^ out1 (verified R4/R5).

#define N_NODES 1024

__device__ __forceinline__ unsigned rotl32(unsigned x, int r) {
  return (x << r) | (x >> (32 - r));
}

// JAX/Random123 Threefry-2x32, 20 rounds.
__device__ __forceinline__ void threefry2x32(unsigned k0, unsigned k1,
                                             unsigned& x0, unsigned& x1) {
  const unsigned ks0 = k0, ks1 = k1, ks2 = k0 ^ k1 ^ 0x1BD11BDAu;
  x0 += ks0; x1 += ks1;
  x0 += x1; x1 = rotl32(x1, 13); x1 ^= x0;
  x0 += x1; x1 = rotl32(x1, 15); x1 ^= x0;
  x0 += x1; x1 = rotl32(x1, 26); x1 ^= x0;
  x0 += x1; x1 = rotl32(x1, 6);  x1 ^= x0;
  x0 += ks1; x1 += ks2 + 1u;
  x0 += x1; x1 = rotl32(x1, 17); x1 ^= x0;
  x0 += x1; x1 = rotl32(x1, 29); x1 ^= x0;
  x0 += x1; x1 = rotl32(x1, 16); x1 ^= x0;
  x0 += x1; x1 = rotl32(x1, 24); x1 ^= x0;
  x0 += ks2; x1 += ks0 + 2u;
  x0 += x1; x1 = rotl32(x1, 13); x1 ^= x0;
  x0 += x1; x1 = rotl32(x1, 15); x1 ^= x0;
  x0 += x1; x1 = rotl32(x1, 26); x1 ^= x0;
  x0 += x1; x1 = rotl32(x1, 6);  x1 ^= x0;
  x0 += ks0; x1 += ks1 + 3u;
  x0 += x1; x1 = rotl32(x1, 17); x1 ^= x0;
  x0 += x1; x1 = rotl32(x1, 29); x1 ^= x0;
  x0 += x1; x1 = rotl32(x1, 16); x1 ^= x0;
  x0 += x1; x1 = rotl32(x1, 24); x1 ^= x0;
  x0 += ks1; x1 += ks2 + 4u;
  x0 += x1; x1 = rotl32(x1, 13); x1 ^= x0;
  x0 += x1; x1 = rotl32(x1, 15); x1 ^= x0;
  x0 += x1; x1 = rotl32(x1, 26); x1 ^= x0;
  x0 += x1; x1 = rotl32(x1, 6);  x1 ^= x0;
  x0 += ks2; x1 += ks0 + 5u;
}

// --- DPP wave-64 reductions (VALU-rate; no LDS) ------------------------------
template <int CTRL>
__device__ __forceinline__ float dpp_sum_step(float v) {
  int t = __builtin_amdgcn_update_dpp(0, __float_as_int(v), CTRL, 0xf, 0xf, true);
  return v + __int_as_float(t);
}
template <int CTRL>
__device__ __forceinline__ float dpp_max_step(float v) {
  int iv = __float_as_int(v);
  int t = __builtin_amdgcn_update_dpp(iv, iv, CTRL, 0xf, 0xf, false);
  return fmaxf(v, __int_as_float(t));
}

__device__ __forceinline__ float wave_sum64(float v) {
  v = dpp_sum_step<0x111>(v);  // row_shr:1
  v = dpp_sum_step<0x112>(v);  // row_shr:2
  v = dpp_sum_step<0x114>(v);  // row_shr:4
  v = dpp_sum_step<0x118>(v);  // row_shr:8
  v = dpp_sum_step<0x142>(v);  // row_bcast:15
  v = dpp_sum_step<0x143>(v);  // row_bcast:31 -> lane 63 has full sum
  return __int_as_float(__builtin_amdgcn_readlane(__float_as_int(v), 63));
}
__device__ __forceinline__ float wave_max64(float v) {
  v = dpp_max_step<0x111>(v);
  v = dpp_max_step<0x112>(v);
  v = dpp_max_step<0x114>(v);
  v = dpp_max_step<0x118>(v);
  v = dpp_max_step<0x142>(v);
  v = dpp_max_step<0x143>(v);
  return __int_as_float(__builtin_amdgcn_readlane(__float_as_int(v), 63));
}

__global__ __launch_bounds__(64, 1)
void Sampler_72619307040792_kernel(const float* __restrict__ att,
                                   const int* __restrict__ kp,
                                   float* __restrict__ out) {
  const int col = blockIdx.x;        // 0..1023 = b*4 + m; ONE wave per column
  const int b = col >> 2;
  const int m = col & 3;
  const int lane = threadIdx.x;      // 64 threads = 1 wave
  const int k = *kp;

  const float EPS = __uint_as_float(0x00800000u);  // f32 tiny (normal min)
  const int base = b * 4096 + m;     // + n*4 indexes element n of this column

  float w[16], kh[16], g[16];

  // --- init: att + Gumbel noise (threefry partitionable, bits = x0^x1), x2
#pragma unroll
  for (int j = 0; j < 16; ++j) {
    const int n = j * 64 + lane;
    const unsigned idx = (unsigned)(base + n * 4);
    unsigned c0 = 0u, c1 = idx;
    threefry2x32(0u, 42u, c0, c1);
    const unsigned bits = c0 ^ c1;
    const float u = __uint_as_float((bits >> 9) | 0x3F800000u) - 1.0f;
    const float gum = -logf(-logf(u + EPS));
    g[j] = 2.0f * (att[idx] + gum);
    kh[j] = 0.0f;
  }

  if (k <= 0) {
#pragma unroll
    for (int j = 0; j < 16; ++j) out[base + (j * 64 + lane) * 4] = 0.0f;
    return;
  }

  // --- column max M0 (uniform shift; exact softmax equivalence)
  float mx = g[0];
#pragma unroll
  for (int j = 1; j < 16; ++j) mx = fmaxf(mx, g[j]);
  mx = wave_max64(mx);

  // --- w_1 = exp(g - M0); S_1; rinv_1
#pragma unroll
  for (int j = 0; j < 16; ++j) w[j] = expf(g[j] - mx);
  {
    float t0 = (w[0] + w[1]) + (w[2] + w[3]);
    float t1 = (w[4] + w[5]) + (w[6] + w[7]);
    float t2 = (w[8] + w[9]) + (w[10] + w[11]);
    float t3 = (w[12] + w[13]) + (w[14] + w[15]);
    float S = wave_sum64((t0 + t1) + (t2 + t3));
    // fall through with rinv in scope below
    float rinv = __builtin_amdgcn_rcpf(S);

    // --- iterations: o = oh_t; kh += o; w *= (1-o)^2; reduce
    for (int it = 1; it < k; ++it) {
      float o[16];
      // phase 1: all o independent
#pragma unroll
      for (int j = 0; j < 16; ++j) o[j] = w[j] * rinv;
      // phase 2: w <- w*(1-o)^2, two fmas each, independent across j
#pragma unroll
      for (int j = 0; j < 16; ++j) {
        const float t = fmaf(-o[j], w[j], w[j]);
        w[j] = fmaf(-o[j], t, t);
      }
      // phase 3: pairwise tree partial sums (depth 4, high ILP)
      float s0 = (w[0] + w[1]) + (w[2] + w[3]);
      float s1 = (w[4] + w[5]) + (w[6] + w[7]);
      float s2 = (w[8] + w[9]) + (w[10] + w[11]);
      float s3 = (w[12] + w[13]) + (w[14] + w[15]);
      float sv = (s0 + s1) + (s2 + s3);
      // phase 4: kh accumulation — independent, fills DPP latency shadow
#pragma unroll
      for (int j = 0; j < 16; ++j) kh[j] += o[j];
      // phase 5: cross-lane sum + rcp
      S = wave_sum64(sv);
      rinv = __builtin_amdgcn_rcpf(S);
    }

    // --- final oh_k accumulation + store
#pragma unroll
    for (int j = 0; j < 16; ++j) {
      kh[j] = fmaf(w[j], rinv, kh[j]);
      out[base + (j * 64 + lane) * 4] = kh[j];
    }
  }
}

extern "C" void kernel_launch(void* const* d_in, const int* in_sizes, int n_in,
                              void* d_out, int out_size, void* d_ws, size_t ws_size,
                              hipStream_t stream) {
  const float* att = (const float*)d_in[0];
  const int* kp = (const int*)d_in[1];
  float* out = (float*)d_out;
  const int cols = out_size / N_NODES;  // 1024 columns, one wave each
  Sampler_72619307040792_kernel<<<cols, 64, 0, stream>>>(att, kp, out);
}